// Round 31
// baseline (441.735 us; speedup 1.0000x reference)
//
#include <hip/hip_runtime.h>

#define TT 2048
#define NQKV 2560   // (H+KVH)*HD = 20*128

typedef _Float16 f16;
typedef _Float16 f16x8 __attribute__((ext_vector_type(8)));
typedef _Float16 f16x4v __attribute__((ext_vector_type(4)));
typedef _Float16 f16x2 __attribute__((ext_vector_type(2)));
typedef float f32x4 __attribute__((ext_vector_type(4)));

#define GLOBAL_AS(p) ((const __attribute__((address_space(1))) void*)(p))
#define LDS_AS(p)    ((__attribute__((address_space(3))) void*)(p))

__device__ __forceinline__ f32x4 mfma_f16(f16x8 a, f16x8 b, f32x4 c) {
  return __builtin_amdgcn_mfma_f32_16x16x32_f16(a, b, c, 0, 0, 0);
}

// ---------------- cast f32 -> f16, 4 elems/thread ----------------
__global__ __launch_bounds__(256) void k_cast_f16(const float* __restrict__ in,
                                                  f16* __restrict__ out, int n4) {
  int i = blockIdx.x * 256 + threadIdx.x;
  if (i >= n4) return;
  float4 v = reinterpret_cast<const float4*>(in)[i];
  f16x4v o;
  o[0] = (f16)v.x; o[1] = (f16)v.y; o[2] = (f16)v.z; o[3] = (f16)v.w;
  reinterpret_cast<f16x4v*>(out)[i] = o;
}

// ---------------- transpose + cast: W (K x N) f32 -> Wt (N x K) f16 ----------------
__global__ __launch_bounds__(256) void k_transpose_f16(const float* __restrict__ W,
                                                       f16* __restrict__ Wt,
                                                       int K, int N) {
  __shared__ f16 tile[32][33];
  int tx = threadIdx.x & 31, ty = threadIdx.x >> 5;  // 32 x 8
  int n0 = blockIdx.x * 32, k0 = blockIdx.y * 32;
  #pragma unroll
  for (int i = ty; i < 32; i += 8)
    tile[i][tx] = (f16)W[(size_t)(k0 + i) * N + n0 + tx];
  __syncthreads();
  #pragma unroll
  for (int i = ty; i < 32; i += 8)
    Wt[(size_t)(n0 + i) * K + k0 + tx] = tile[tx][i];
}

// ---------------- MFMA f16 GEMM with global_load_lds staging ----------------
template<int BM, int BN, int WGM, int WGN>
__global__ __launch_bounds__(256) void gemm_bt_kernel(
    const f16* __restrict__ A, const f16* __restrict__ Bt,
    f16* __restrict__ C, int M, int N, int K)
{
  constexpr int BK = 32;
  constexpr int WM = BM / WGM, WN = BN / WGN;
  constexpr int FM = WM / 16, FN = WN / 16;
  constexpr int ACH = BM * 4;
  constexpr int TCH = (BM + BN) * 4;
  __shared__ alignas(16) f16 lds[(BM + BN) * BK];
  const int tid = threadIdx.x;
  const int lane = tid & 63;
  const int w = tid >> 6;
  const int l15 = lane & 15, grp = lane >> 4;
  const int wm = w / WGN, wn = w % WGN;
  const int m0 = blockIdx.y * BM, n0 = blockIdx.x * BN;

  f32x4 acc[FM][FN];
  #pragma unroll
  for (int i = 0; i < FM; ++i)
    #pragma unroll
    for (int j = 0; j < FN; ++j)
      acc[i][j] = (f32x4){0.f, 0.f, 0.f, 0.f};

  const int nk = K / BK;
  for (int kt = 0; kt < nk; ++kt) {
    __syncthreads();
    for (int c = tid; c < TCH; c += 256) {
      const f16* gp;
      if (c < ACH) {
        int row = c >> 2;
        gp = A + (size_t)(m0 + row) * K + kt * BK + (c & 3) * 8;
      } else {
        int cc = c - ACH;
        int row = cc >> 2;
        gp = Bt + (size_t)(n0 + row) * K + kt * BK + (cc & 3) * 8;
      }
      __builtin_amdgcn_global_load_lds(GLOBAL_AS(gp),
                                       LDS_AS((char*)lds + (size_t)c * 16),
                                       16, 0, 0);
    }
    __syncthreads();
    f16x8 af[FM], bfr[FN];
    #pragma unroll
    for (int i = 0; i < FM; ++i)
      af[i] = *reinterpret_cast<const f16x8*>(
          (const char*)lds + (size_t)(wm * WM + i * 16 + l15) * 64 + grp * 16);
    #pragma unroll
    for (int j = 0; j < FN; ++j)
      bfr[j] = *reinterpret_cast<const f16x8*>(
          (const char*)lds + (size_t)(BM + wn * WN + j * 16 + l15) * 64 + grp * 16);
    #pragma unroll
    for (int i = 0; i < FM; ++i)
      #pragma unroll
      for (int j = 0; j < FN; ++j)
        acc[i][j] = mfma_f16(af[i], bfr[j], acc[i][j]);
  }
  #pragma unroll
  for (int i = 0; i < FM; ++i)
    #pragma unroll
    for (int j = 0; j < FN; ++j)
      #pragma unroll
      for (int r = 0; r < 4; ++r) {
        int row = m0 + wm * WM + i * 16 + grp * 4 + r;
        int col = n0 + wn * WN + j * 16 + l15;
        C[(size_t)row * N + col] = (f16)acc[i][j][r];
      }
}

// ---------------- lambda_full scalar ----------------
__global__ void k_lambda(const float* __restrict__ lq1, const float* __restrict__ lk1,
                         const float* __restrict__ lq2, const float* __restrict__ lk2,
                         float* __restrict__ lam) {
  int lane = threadIdx.x;
  float a = lq1[lane] * lk1[lane];
  float c = lq2[lane] * lk2[lane];
  #pragma unroll
  for (int m = 1; m < 64; m <<= 1) {
    a += __shfl_xor(a, m);
    c += __shfl_xor(c, m);
  }
  if (lane == 0) lam[0] = expf(a) - expf(c) + 0.2f;  // LAMBDA_INIT = 0.2
}

// ---------------- build Q/K/Vt: RMSNorm + RoPE + scaling, f16 in/out ----------------
__global__ __launch_bounds__(256) void k_build(
    const f16* __restrict__ qkv, const f16* __restrict__ krope,
    const float* __restrict__ brope, const float* __restrict__ scaler,
    f16* __restrict__ Qo, f16* __restrict__ Ko, f16* __restrict__ Vto)
{
  const int blk = blockIdx.x;
  const int b = blk >> 11, t = blk & 2047;
  const int tid = threadIdx.x;
  const int lane = tid & 63, w = tid >> 6;
  __shared__ float nrm[20][128];
  __shared__ float cs[32], sn[32];
  if (tid < 32) {
    const float inv = expf(-(float)(2 * tid) * (9.210340371976184f / 64.0f));
    const float fr = (float)t * inv;
    cs[tid] = cosf(fr);
    sn[tid] = sinf(fr);
  }
  const f16* row = qkv + (size_t)blk * NQKV;
  #pragma unroll
  for (int i = 0; i < 5; ++i) {
    const int hh = w + 4 * i;  // 0..19
    f16x2 v = *reinterpret_cast<const f16x2*>(row + hh * 128 + lane * 2);
    float vx = (float)v[0], vy = (float)v[1];
    float ss = vx * vx + vy * vy;
    #pragma unroll
    for (int m = 1; m < 64; m <<= 1) ss += __shfl_xor(ss, m);
    const float r = rsqrtf(ss * (1.0f / 128.0f) + 1e-6f);
    nrm[hh][lane * 2]     = vx * r;
    nrm[hh][lane * 2 + 1] = vy * r;
  }
  __syncthreads();
  const float lg = logf((float)(t + 1));
  {
    const int h = tid >> 4, dc = (tid & 15) * 8;
    const float sc = scaler[h] * lg * 0.08838834764831845f;  // 1/sqrt(128)
    f16x8 ov;
    if (dc < 64) {
      #pragma unroll
      for (int j = 0; j < 8; ++j) ov[j] = (f16)(nrm[h][dc + j] * sc);
    } else if (dc < 96) {
      #pragma unroll
      for (int j = 0; j < 8; ++j) {
        int jj = dc - 64 + j;
        ov[j] = (f16)((nrm[h][64 + jj] * cs[jj] + nrm[h][96 + jj] * sn[jj]) * sc);
      }
    } else {
      #pragma unroll
      for (int j = 0; j < 8; ++j) {
        int jj = dc - 96 + j;
        ov[j] = (f16)((-nrm[h][64 + jj] * sn[jj] + nrm[h][96 + jj] * cs[jj]) * sc);
      }
    }
    *reinterpret_cast<f16x8*>(Qo + ((size_t)(b * 16 + h) * TT + t) * 128 + dc) = ov;
  }
  if (tid < 64) {
    const int gg = tid >> 4, dc = (tid & 15) * 8;
    f16x8 ov;
    if (dc < 64) {
      #pragma unroll
      for (int j = 0; j < 8; ++j) ov[j] = (f16)nrm[16 + gg][dc + j];
    } else if (dc < 96) {
      #pragma unroll
      for (int j = 0; j < 8; ++j) {
        int jj = dc - 64 + j;
        float k1v = (float)krope[(size_t)blk * 64 + jj] + brope[jj];
        float k2v = (float)krope[(size_t)blk * 64 + 32 + jj] + brope[32 + jj];
        ov[j] = (f16)(k1v * cs[jj] + k2v * sn[jj]);
      }
    } else {
      #pragma unroll
      for (int j = 0; j < 8; ++j) {
        int jj = dc - 96 + j;
        float k1v = (float)krope[(size_t)blk * 64 + jj] + brope[jj];
        float k2v = (float)krope[(size_t)blk * 64 + 32 + jj] + brope[32 + jj];
        ov[j] = (f16)(-k1v * sn[jj] + k2v * cs[jj]);
      }
    }
    *reinterpret_cast<f16x8*>(Ko + ((size_t)(b * 4 + gg) * TT + t) * 128 + dc) = ov;
  }
  for (int i = tid; i < 512; i += 256) {
    const int gg = i >> 7, d = i & 127;
    Vto[((size_t)(b * 4 + gg) * 128 + d) * TT + t] = (f16)nrm[16 + gg][d];
  }
}

// ---------------- flash v7: 4-way KV split (strided tiles), m/l merge ----------------
// grid = (T/16, 8, B), block = 256 (4 waves). All waves share 16 q-rows / head pair;
// wave w processes tiles it = w, w+4, ...; waves 1-3 publish partials; wave 0 merges.
__global__ __launch_bounds__(256) void flash_kernel(
    const f16* __restrict__ Q, const f16* __restrict__ Kt,
    const f16* __restrict__ Vt, const float* __restrict__ lamp,
    float* __restrict__ out)
{
  const int tid = threadIdx.x;
  const int w = tid >> 6;          // 0..3 KV split
  const int lane = tid & 63;
  const int l15 = lane & 15, grp = lane >> 4;
  const int qt = blockIdx.x;   // T/16
  const int p  = blockIdx.y;   // 8
  const int b  = blockIdx.z;   // B
  const int g  = p >> 1;
  const int qbase = qt * 16;

  __shared__ alignas(16) f16 Plds[4][2][16][40];  // [wave][head][row][32+pad]
  __shared__ float Mbuf[3][2][4][64];             // waves 1-3 partial m
  __shared__ float Lbuf[3][2][4][64];             // waves 1-3 partial l
  __shared__ f16   Obuf[3][2][8][4][64];          // waves 1-3 normalized partial y

  f16x8 qf[2][4];
  #pragma unroll
  for (int hh = 0; hh < 2; ++hh) {
    const f16* qp = Q + ((size_t)(b * 16 + 2 * p + hh) * TT + qbase + l15) * 128 + grp * 8;
    #pragma unroll
    for (int kc = 0; kc < 4; ++kc) qf[hh][kc] = *reinterpret_cast<const f16x8*>(qp + kc * 32);
  }

  f32x4 o[2][8];
  #pragma unroll
  for (int hh = 0; hh < 2; ++hh)
    #pragma unroll
    for (int cb = 0; cb < 8; ++cb) o[hh][cb] = (f32x4){0.f, 0.f, 0.f, 0.f};
  float mrow[2][4], lrow[2][4];
  #pragma unroll
  for (int hh = 0; hh < 2; ++hh)
    #pragma unroll
    for (int r = 0; r < 4; ++r) { mrow[hh][r] = -1e30f; lrow[hh][r] = 0.f; }

  const f16* kb = Kt + (size_t)(b * 4 + g) * TT * 128;
  const f16* vb = Vt + (size_t)(b * 4 + g) * 128 * TT;

  const int ntt = qt / 2 + 1;          // total 32-key tiles
  for (int it = w; it < ntt; it += 4) {
    const int s0 = it * 32;
    f32x4 s[2][2];
    #pragma unroll
    for (int hh = 0; hh < 2; ++hh)
      #pragma unroll
      for (int st = 0; st < 2; ++st) s[hh][st] = (f32x4){0.f, 0.f, 0.f, 0.f};
    #pragma unroll
    for (int st = 0; st < 2; ++st) {
      #pragma unroll
      for (int kc = 0; kc < 4; ++kc) {
        f16x8 kf = *reinterpret_cast<const f16x8*>(
            kb + (size_t)(s0 + st * 16 + l15) * 128 + kc * 32 + grp * 8);
        s[0][st] = mfma_f16(qf[0][kc], kf, s[0][st]);
        s[1][st] = mfma_f16(qf[1][kc], kf, s[1][st]);
      }
    }
    if (s0 + 31 > qbase) {
      #pragma unroll
      for (int st = 0; st < 2; ++st) {
        const int sidx = s0 + st * 16 + l15;
        #pragma unroll
        for (int r = 0; r < 4; ++r) {
          if (sidx > qbase + grp * 4 + r) { s[0][st][r] = -1e30f; s[1][st][r] = -1e30f; }
        }
      }
    }
    #pragma unroll
    for (int hh = 0; hh < 2; ++hh) {
      float fsc[4];
      int need = 0;
      #pragma unroll
      for (int r = 0; r < 4; ++r) {
        float mx = fmaxf(s[hh][0][r], s[hh][1][r]);
        mx = fmaxf(mx, __shfl_xor(mx, 1));
        mx = fmaxf(mx, __shfl_xor(mx, 2));
        mx = fmaxf(mx, __shfl_xor(mx, 4));
        mx = fmaxf(mx, __shfl_xor(mx, 8));
        const float mnew = fmaxf(mrow[hh][r], mx);
        fsc[r] = __expf(mrow[hh][r] - mnew);
        mrow[hh][r] = mnew;
        const float p0 = __expf(s[hh][0][r] - mnew);
        const float p1 = __expf(s[hh][1][r] - mnew);
        float rs = p0 + p1;
        rs += __shfl_xor(rs, 1);
        rs += __shfl_xor(rs, 2);
        rs += __shfl_xor(rs, 4);
        rs += __shfl_xor(rs, 8);
        lrow[hh][r] = lrow[hh][r] * fsc[r] + rs;
        Plds[w][hh][grp * 4 + r][l15]      = (f16)p0;
        Plds[w][hh][grp * 4 + r][16 + l15] = (f16)p1;
        need |= (fsc[r] != 1.f);
      }
      if (__any(need)) {
        #pragma unroll
        for (int cb = 0; cb < 8; ++cb)
          #pragma unroll
          for (int r = 0; r < 4; ++r) o[hh][cb][r] *= fsc[r];
      }
    }
    // per-wave LDS fence: P writes complete before reads (DS in-order per wave)
    asm volatile("s_waitcnt lgkmcnt(0)" ::: "memory");
    f16x8 pa0 = *reinterpret_cast<const f16x8*>(&Plds[w][0][l15][grp * 8]);
    f16x8 pa1 = *reinterpret_cast<const f16x8*>(&Plds[w][1][l15][grp * 8]);
    #pragma unroll
    for (int cb = 0; cb < 8; ++cb) {
      f16x8 vf = *reinterpret_cast<const f16x8*>(
          vb + (size_t)(cb * 16 + l15) * TT + s0 + grp * 8);
      o[0][cb] = mfma_f16(pa0, vf, o[0][cb]);
      o[1][cb] = mfma_f16(pa1, vf, o[1][cb]);
    }
  }
  // ---- waves 1-3 publish normalized partials ----
  if (w > 0) {
    #pragma unroll
    for (int hh = 0; hh < 2; ++hh)
      #pragma unroll
      for (int r = 0; r < 4; ++r) {
        Mbuf[w - 1][hh][r][lane] = mrow[hh][r];
        Lbuf[w - 1][hh][r][lane] = lrow[hh][r];
        const float inv = lrow[hh][r] > 0.f ? 1.f / lrow[hh][r] : 0.f;
        #pragma unroll
        for (int cb = 0; cb < 8; ++cb)
          Obuf[w - 1][hh][cb][r][lane] = (f16)(o[hh][cb][r] * inv);
      }
  }
  __syncthreads();
  // ---- wave 0 merges 4 partials and writes output ----
  if (w == 0) {
    const float lam = lamp[0];
    #pragma unroll
    for (int hh = 0; hh < 2; ++hh) {
      #pragma unroll
      for (int r = 0; r < 4; ++r) {
        float M = mrow[hh][r];
        #pragma unroll
        for (int j = 0; j < 3; ++j) M = fmaxf(M, Mbuf[j][hh][r][lane]);
        const float a0 = __expf(mrow[hh][r] - M);
        float wj[3];
        float den = a0 * lrow[hh][r];
        #pragma unroll
        for (int j = 0; j < 3; ++j) {
          wj[j] = __expf(Mbuf[j][hh][r][lane] - M) * Lbuf[j][hh][r][lane];
          den += wj[j];
        }
        const float inv = 1.f / den;
        #pragma unroll
        for (int cb = 0; cb < 8; ++cb) {
          float y = a0 * o[hh][cb][r];
          #pragma unroll
          for (int j = 0; j < 3; ++j)
            y += wj[j] * (float)Obuf[j][hh][cb][r][lane];
          o[hh][cb][r] = y * inv;
        }
      }
    }
    #pragma unroll
    for (int cb = 0; cb < 8; ++cb) {
      #pragma unroll
      for (int r = 0; r < 4; ++r) {
        const float y = o[0][cb][r] - lam * o[1][cb][r];
        const int t = qbase + grp * 4 + r;
        const size_t base = (((size_t)b * TT + t) * 8 + p) * 256 + cb * 16 + l15;
        out[base] = y;
        out[base + 128] = y;
      }
    }
  }
}

extern "C" void kernel_launch(void* const* d_in, const int* in_sizes, int n_in,
                              void* d_out, int out_size, void* d_ws, size_t ws_size,
                              hipStream_t stream) {
  (void)out_size; (void)ws_size;
  int ix = 0, iwq = 1, iwr = 2, isc = 4;
  int idx64[8]; int n64 = 0;
  for (int i = 0; i < n_in; ++i) {
    if (in_sizes[i] == 8388608) ix = i;
    else if (in_sizes[i] == 5242880) iwq = i;
    else if (in_sizes[i] == 131072) iwr = i;
    else if (in_sizes[i] == 16) isc = i;
    else if (in_sizes[i] == 64 && n64 < 8) idx64[n64++] = i;
  }
  int ibr = 3, ilq1 = 5, ilk1 = 6, ilq2 = 7, ilk2 = 8;
  if (n64 == 5) { ibr = idx64[0]; ilq1 = idx64[1]; ilk1 = idx64[2]; ilq2 = idx64[3]; ilk2 = idx64[4]; }

  const float* x   = (const float*)d_in[ix];
  const float* Wq  = (const float*)d_in[iwq];
  const float* Wr  = (const float*)d_in[iwr];
  const float* br  = (const float*)d_in[ibr];
  const float* sc  = (const float*)d_in[isc];
  const float* lq1 = (const float*)d_in[ilq1];
  const float* lk1 = (const float*)d_in[ilk1];
  const float* lq2 = (const float*)d_in[ilq2];
  const float* lk2 = (const float*)d_in[ilk2];
  float* out = (float*)d_out;   // FLOAT32 output (validated round 24)

  char* ws = (char*)d_ws;
  f16*   xb    = (f16*)  (ws + 0);
  f16*   wtq   = (f16*)  (ws + 16777216);
  f16*   wtr   = (f16*)  (ws + 27262976);
  f16*   qkv16 = (f16*)  (ws + 27525120);
  f16*   kro16 = (f16*)  (ws + 48496640);
  float* lam   = (float*)(ws + 49020928);
  f16*   Qo    = (f16*)  (ws + 0);
  f16*   Ko    = (f16*)  (ws + 16777216);
  f16*   Vto   = (f16*)  (ws + 20971520);

  k_cast_f16<<<dim3(8192), dim3(256), 0, stream>>>(x, xb, 2097152);
  k_transpose_f16<<<dim3(80, 64), dim3(256), 0, stream>>>(Wq, wtq, 2048, 2560);
  k_transpose_f16<<<dim3(2, 64), dim3(256), 0, stream>>>(Wr, wtr, 2048, 64);
  gemm_bt_kernel<128, 128, 2, 2><<<dim3(20, 32), dim3(256), 0, stream>>>(
      xb, wtq, qkv16, 4096, 2560, 2048);
  gemm_bt_kernel<128, 64, 4, 1><<<dim3(1, 32), dim3(256), 0, stream>>>(
      xb, wtr, kro16, 4096, 64, 2048);
  k_lambda<<<dim3(1), dim3(64), 0, stream>>>(lq1, lk1, lq2, lk2, lam);
  k_build<<<dim3(4096), dim3(256), 0, stream>>>(qkv16, kro16, br, sc, Qo, Ko, Vto);
  flash_kernel<<<dim3(128, 8, 2), dim3(256), 0, stream>>>(Qo, Ko, Vto, lam, out);
}

// Round 32
// 322.720 us; speedup vs baseline: 1.3688x; 1.3688x over previous
//
#include <hip/hip_runtime.h>

#define TT 2048

typedef _Float16 f16;
typedef _Float16 f16x8 __attribute__((ext_vector_type(8)));
typedef _Float16 f16x4v __attribute__((ext_vector_type(4)));
typedef _Float16 f16x2 __attribute__((ext_vector_type(2)));
typedef float f32x4 __attribute__((ext_vector_type(4)));

#define GLOBAL_AS(p) ((const __attribute__((address_space(1))) void*)(p))
#define LDS_AS(p)    ((__attribute__((address_space(3))) void*)(p))

__device__ __forceinline__ f32x4 mfma_f16(f16x8 a, f16x8 b, f32x4 c) {
  return __builtin_amdgcn_mfma_f32_16x16x32_f16(a, b, c, 0, 0, 0);
}

// ---------------- cast f32 -> f16, 4 elems/thread ----------------
__global__ __launch_bounds__(256) void k_cast_f16(const float* __restrict__ in,
                                                  f16* __restrict__ out, int n4) {
  int i = blockIdx.x * 256 + threadIdx.x;
  if (i >= n4) return;
  float4 v = reinterpret_cast<const float4*>(in)[i];
  f16x4v o;
  o[0] = (f16)v.x; o[1] = (f16)v.y; o[2] = (f16)v.z; o[3] = (f16)v.w;
  reinterpret_cast<f16x4v*>(out)[i] = o;
}

// ---------------- transpose + cast: W (K x N) f32 -> Wt (N x K) f16 ----------------
__global__ __launch_bounds__(256) void k_transpose_f16(const float* __restrict__ W,
                                                       f16* __restrict__ Wt,
                                                       int K, int N) {
  __shared__ f16 tile[32][33];
  int tx = threadIdx.x & 31, ty = threadIdx.x >> 5;  // 32 x 8
  int n0 = blockIdx.x * 32, k0 = blockIdx.y * 32;
  #pragma unroll
  for (int i = ty; i < 32; i += 8)
    tile[i][tx] = (f16)W[(size_t)(k0 + i) * N + n0 + tx];
  __syncthreads();
  #pragma unroll
  for (int i = ty; i < 32; i += 8)
    Wt[(size_t)(n0 + i) * K + k0 + tx] = tile[tx][i];
}

// ---------------- MFMA f16 GEMM with global_load_lds staging ----------------
template<int BM, int BN, int WGM, int WGN>
__global__ __launch_bounds__(256) void gemm_bt_kernel(
    const f16* __restrict__ A, const f16* __restrict__ Bt,
    f16* __restrict__ C, int M, int N, int K)
{
  constexpr int BK = 32;
  constexpr int WM = BM / WGM, WN = BN / WGN;
  constexpr int FM = WM / 16, FN = WN / 16;
  constexpr int ACH = BM * 4;
  constexpr int TCH = (BM + BN) * 4;
  __shared__ alignas(16) f16 lds[(BM + BN) * BK];
  const int tid = threadIdx.x;
  const int lane = tid & 63;
  const int w = tid >> 6;
  const int l15 = lane & 15, grp = lane >> 4;
  const int wm = w / WGN, wn = w % WGN;
  const int m0 = blockIdx.y * BM, n0 = blockIdx.x * BN;

  f32x4 acc[FM][FN];
  #pragma unroll
  for (int i = 0; i < FM; ++i)
    #pragma unroll
    for (int j = 0; j < FN; ++j)
      acc[i][j] = (f32x4){0.f, 0.f, 0.f, 0.f};

  const int nk = K / BK;
  for (int kt = 0; kt < nk; ++kt) {
    __syncthreads();
    for (int c = tid; c < TCH; c += 256) {
      const f16* gp;
      if (c < ACH) {
        int row = c >> 2;
        gp = A + (size_t)(m0 + row) * K + kt * BK + (c & 3) * 8;
      } else {
        int cc = c - ACH;
        int row = cc >> 2;
        gp = Bt + (size_t)(n0 + row) * K + kt * BK + (cc & 3) * 8;
      }
      __builtin_amdgcn_global_load_lds(GLOBAL_AS(gp),
                                       LDS_AS((char*)lds + (size_t)c * 16),
                                       16, 0, 0);
    }
    __syncthreads();
    f16x8 af[FM], bfr[FN];
    #pragma unroll
    for (int i = 0; i < FM; ++i)
      af[i] = *reinterpret_cast<const f16x8*>(
          (const char*)lds + (size_t)(wm * WM + i * 16 + l15) * 64 + grp * 16);
    #pragma unroll
    for (int j = 0; j < FN; ++j)
      bfr[j] = *reinterpret_cast<const f16x8*>(
          (const char*)lds + (size_t)(BM + wn * WN + j * 16 + l15) * 64 + grp * 16);
    #pragma unroll
    for (int i = 0; i < FM; ++i)
      #pragma unroll
      for (int j = 0; j < FN; ++j)
        acc[i][j] = mfma_f16(af[i], bfr[j], acc[i][j]);
  }
  #pragma unroll
  for (int i = 0; i < FM; ++i)
    #pragma unroll
    for (int j = 0; j < FN; ++j)
      #pragma unroll
      for (int r = 0; r < 4; ++r) {
        int row = m0 + wm * WM + i * 16 + grp * 4 + r;
        int col = n0 + wn * WN + j * 16 + l15;
        C[(size_t)row * N + col] = (f16)acc[i][j][r];
      }
}

// ---------------- lambda_full scalar ----------------
__global__ void k_lambda(const float* __restrict__ lq1, const float* __restrict__ lk1,
                         const float* __restrict__ lq2, const float* __restrict__ lk2,
                         float* __restrict__ lam) {
  int lane = threadIdx.x;
  float a = lq1[lane] * lk1[lane];
  float c = lq2[lane] * lk2[lane];
  #pragma unroll
  for (int m = 1; m < 64; m <<= 1) {
    a += __shfl_xor(a, m);
    c += __shfl_xor(c, m);
  }
  if (lane == 0) lam[0] = expf(a) - expf(c) + 0.2f;  // LAMBDA_INIT = 0.2
}

// ---------------- build Q/K/Vt from fused qkv+krope rows (stride 2624) ----------------
__global__ __launch_bounds__(256) void k_build(
    const f16* __restrict__ qkvr,
    const float* __restrict__ brope, const float* __restrict__ scaler,
    f16* __restrict__ Qo, f16* __restrict__ Ko, f16* __restrict__ Vto)
{
  const int blk = blockIdx.x;
  const int b = blk >> 11, t = blk & 2047;
  const int tid = threadIdx.x;
  const int lane = tid & 63, w = tid >> 6;
  __shared__ float nrm[20][128];
  __shared__ float cs[32], sn[32];
  if (tid < 32) {
    const float inv = expf(-(float)(2 * tid) * (9.210340371976184f / 64.0f));
    const float fr = (float)t * inv;
    cs[tid] = cosf(fr);
    sn[tid] = sinf(fr);
  }
  const f16* row = qkvr + (size_t)blk * 2624;
  #pragma unroll
  for (int i = 0; i < 5; ++i) {
    const int hh = w + 4 * i;  // 0..19
    f16x2 v = *reinterpret_cast<const f16x2*>(row + hh * 128 + lane * 2);
    float vx = (float)v[0], vy = (float)v[1];
    float ss = vx * vx + vy * vy;
    #pragma unroll
    for (int m = 1; m < 64; m <<= 1) ss += __shfl_xor(ss, m);
    const float r = rsqrtf(ss * (1.0f / 128.0f) + 1e-6f);
    nrm[hh][lane * 2]     = vx * r;
    nrm[hh][lane * 2 + 1] = vy * r;
  }
  __syncthreads();
  const float lg = logf((float)(t + 1));
  {
    const int h = tid >> 4, dc = (tid & 15) * 8;
    const float sc = scaler[h] * lg * 0.08838834764831845f;  // 1/sqrt(128)
    f16x8 ov;
    if (dc < 64) {
      #pragma unroll
      for (int j = 0; j < 8; ++j) ov[j] = (f16)(nrm[h][dc + j] * sc);
    } else if (dc < 96) {
      #pragma unroll
      for (int j = 0; j < 8; ++j) {
        int jj = dc - 64 + j;
        ov[j] = (f16)((nrm[h][64 + jj] * cs[jj] + nrm[h][96 + jj] * sn[jj]) * sc);
      }
    } else {
      #pragma unroll
      for (int j = 0; j < 8; ++j) {
        int jj = dc - 96 + j;
        ov[j] = (f16)((-nrm[h][64 + jj] * sn[jj] + nrm[h][96 + jj] * cs[jj]) * sc);
      }
    }
    *reinterpret_cast<f16x8*>(Qo + ((size_t)(b * 16 + h) * TT + t) * 128 + dc) = ov;
  }
  if (tid < 64) {
    const int gg = tid >> 4, dc = (tid & 15) * 8;
    f16x8 ov;
    if (dc < 64) {
      #pragma unroll
      for (int j = 0; j < 8; ++j) ov[j] = (f16)nrm[16 + gg][dc + j];
    } else if (dc < 96) {
      #pragma unroll
      for (int j = 0; j < 8; ++j) {
        int jj = dc - 64 + j;
        float k1v = (float)row[2560 + jj] + brope[jj];
        float k2v = (float)row[2560 + 32 + jj] + brope[32 + jj];
        ov[j] = (f16)(k1v * cs[jj] + k2v * sn[jj]);
      }
    } else {
      #pragma unroll
      for (int j = 0; j < 8; ++j) {
        int jj = dc - 96 + j;
        float k1v = (float)row[2560 + jj] + brope[jj];
        float k2v = (float)row[2560 + 32 + jj] + brope[32 + jj];
        ov[j] = (f16)(-k1v * sn[jj] + k2v * cs[jj]);
      }
    }
    *reinterpret_cast<f16x8*>(Ko + ((size_t)(b * 4 + gg) * TT + t) * 128 + dc) = ov;
  }
  for (int i = tid; i < 512; i += 256) {
    const int gg = i >> 7, d = i & 127;
    Vto[((size_t)(b * 4 + gg) * 128 + d) * TT + t] = (f16)nrm[16 + gg][d];
  }
}

// ---------------- flash v8: diagonal-paired balanced blocks, 2 independent waves ----------------
// grid = (64, 8, B), block = 128. Wave 0 owns q-tile bx, wave 1 owns q-tile 127-bx;
// combined work = 64+-1 KV tiles per block (perfectly balanced). No inter-wave comm.
__global__ __launch_bounds__(128) void flash_kernel(
    const f16* __restrict__ Q, const f16* __restrict__ Kt,
    const f16* __restrict__ Vt, const float* __restrict__ lamp,
    float* __restrict__ out)
{
  const int tid = threadIdx.x;
  const int w = tid >> 6;
  const int lane = tid & 63;
  const int l15 = lane & 15, grp = lane >> 4;
  const int qt = (w == 0) ? (int)blockIdx.x : (127 - (int)blockIdx.x);
  const int p  = blockIdx.y;   // 8
  const int b  = blockIdx.z;   // B
  const int g  = p >> 1;
  const int qbase = qt * 16;

  __shared__ alignas(16) f16 Plds[2][2][16][40];  // [wave][head][row][32+pad]

  f16x8 qf[2][4];
  #pragma unroll
  for (int hh = 0; hh < 2; ++hh) {
    const f16* qp = Q + ((size_t)(b * 16 + 2 * p + hh) * TT + qbase + l15) * 128 + grp * 8;
    #pragma unroll
    for (int kc = 0; kc < 4; ++kc) qf[hh][kc] = *reinterpret_cast<const f16x8*>(qp + kc * 32);
  }

  f32x4 o[2][8];
  #pragma unroll
  for (int hh = 0; hh < 2; ++hh)
    #pragma unroll
    for (int cb = 0; cb < 8; ++cb) o[hh][cb] = (f32x4){0.f, 0.f, 0.f, 0.f};
  float mrow[2][4], lrow[2][4];
  #pragma unroll
  for (int hh = 0; hh < 2; ++hh)
    #pragma unroll
    for (int r = 0; r < 4; ++r) { mrow[hh][r] = -1e30f; lrow[hh][r] = 0.f; }

  const f16* kb = Kt + (size_t)(b * 4 + g) * TT * 128;
  const f16* vb = Vt + (size_t)(b * 4 + g) * 128 * TT;

  const int nt = qbase / 32 + 1;  // 32-key tiles
  for (int it = 0; it < nt; ++it) {
    const int s0 = it * 32;
    f32x4 s[2][2];
    #pragma unroll
    for (int hh = 0; hh < 2; ++hh)
      #pragma unroll
      for (int st = 0; st < 2; ++st) s[hh][st] = (f32x4){0.f, 0.f, 0.f, 0.f};
    #pragma unroll
    for (int st = 0; st < 2; ++st) {
      #pragma unroll
      for (int kc = 0; kc < 4; ++kc) {
        f16x8 kf = *reinterpret_cast<const f16x8*>(
            kb + (size_t)(s0 + st * 16 + l15) * 128 + kc * 32 + grp * 8);
        s[0][st] = mfma_f16(qf[0][kc], kf, s[0][st]);
        s[1][st] = mfma_f16(qf[1][kc], kf, s[1][st]);
      }
    }
    if (s0 + 31 > qbase) {
      #pragma unroll
      for (int st = 0; st < 2; ++st) {
        const int sidx = s0 + st * 16 + l15;
        #pragma unroll
        for (int r = 0; r < 4; ++r) {
          if (sidx > qbase + grp * 4 + r) { s[0][st][r] = -1e30f; s[1][st][r] = -1e30f; }
        }
      }
    }
    #pragma unroll
    for (int hh = 0; hh < 2; ++hh) {
      float fsc[4];
      int need = 0;
      #pragma unroll
      for (int r = 0; r < 4; ++r) {
        float mx = fmaxf(s[hh][0][r], s[hh][1][r]);
        mx = fmaxf(mx, __shfl_xor(mx, 1));
        mx = fmaxf(mx, __shfl_xor(mx, 2));
        mx = fmaxf(mx, __shfl_xor(mx, 4));
        mx = fmaxf(mx, __shfl_xor(mx, 8));
        const float mnew = fmaxf(mrow[hh][r], mx);
        fsc[r] = __expf(mrow[hh][r] - mnew);
        mrow[hh][r] = mnew;
        const float p0 = __expf(s[hh][0][r] - mnew);
        const float p1 = __expf(s[hh][1][r] - mnew);
        float rs = p0 + p1;
        rs += __shfl_xor(rs, 1);
        rs += __shfl_xor(rs, 2);
        rs += __shfl_xor(rs, 4);
        rs += __shfl_xor(rs, 8);
        lrow[hh][r] = lrow[hh][r] * fsc[r] + rs;
        Plds[w][hh][grp * 4 + r][l15]      = (f16)p0;
        Plds[w][hh][grp * 4 + r][16 + l15] = (f16)p1;
        need |= (fsc[r] != 1.f);
      }
      if (__any(need)) {
        #pragma unroll
        for (int cb = 0; cb < 8; ++cb)
          #pragma unroll
          for (int r = 0; r < 4; ++r) o[hh][cb][r] *= fsc[r];
      }
    }
    // per-wave LDS fence (DS ops in-order per wave; no cross-wave sharing)
    asm volatile("s_waitcnt lgkmcnt(0)" ::: "memory");
    f16x8 pa0 = *reinterpret_cast<const f16x8*>(&Plds[w][0][l15][grp * 8]);
    f16x8 pa1 = *reinterpret_cast<const f16x8*>(&Plds[w][1][l15][grp * 8]);
    #pragma unroll
    for (int cb = 0; cb < 8; ++cb) {
      f16x8 vf = *reinterpret_cast<const f16x8*>(
          vb + (size_t)(cb * 16 + l15) * TT + s0 + grp * 8);
      o[0][cb] = mfma_f16(pa0, vf, o[0][cb]);
      o[1][cb] = mfma_f16(pa1, vf, o[1][cb]);
    }
  }
  // ---- epilogue: per-wave differential combine, f32 out, duplicated halves ----
  const float lam = lamp[0];
  float inv0[4], inv1[4];
  #pragma unroll
  for (int r = 0; r < 4; ++r) {
    inv0[r] = 1.f / lrow[0][r];
    inv1[r] = 1.f / lrow[1][r];
  }
  #pragma unroll
  for (int cb = 0; cb < 8; ++cb) {
    #pragma unroll
    for (int r = 0; r < 4; ++r) {
      const float y = o[0][cb][r] * inv0[r] - lam * (o[1][cb][r] * inv1[r]);
      const int t = qbase + grp * 4 + r;
      const size_t base = (((size_t)b * TT + t) * 8 + p) * 256 + cb * 16 + l15;
      out[base] = y;
      out[base + 128] = y;
    }
  }
}

extern "C" void kernel_launch(void* const* d_in, const int* in_sizes, int n_in,
                              void* d_out, int out_size, void* d_ws, size_t ws_size,
                              hipStream_t stream) {
  (void)out_size; (void)ws_size;
  int ix = 0, iwq = 1, iwr = 2, isc = 4;
  int idx64[8]; int n64 = 0;
  for (int i = 0; i < n_in; ++i) {
    if (in_sizes[i] == 8388608) ix = i;
    else if (in_sizes[i] == 5242880) iwq = i;
    else if (in_sizes[i] == 131072) iwr = i;
    else if (in_sizes[i] == 16) isc = i;
    else if (in_sizes[i] == 64 && n64 < 8) idx64[n64++] = i;
  }
  int ibr = 3, ilq1 = 5, ilk1 = 6, ilq2 = 7, ilk2 = 8;
  if (n64 == 5) { ibr = idx64[0]; ilq1 = idx64[1]; ilk1 = idx64[2]; ilq2 = idx64[3]; ilk2 = idx64[4]; }

  const float* x   = (const float*)d_in[ix];
  const float* Wq  = (const float*)d_in[iwq];
  const float* Wr  = (const float*)d_in[iwr];
  const float* br  = (const float*)d_in[ibr];
  const float* sc  = (const float*)d_in[isc];
  const float* lq1 = (const float*)d_in[ilq1];
  const float* lk1 = (const float*)d_in[ilk1];
  const float* lq2 = (const float*)d_in[ilq2];
  const float* lk2 = (const float*)d_in[ilk2];
  float* out = (float*)d_out;   // FLOAT32 output (validated round 24)

  // Workspace:
  //  phase 1: xb[0,16.78M) wt[16.78M,27.53M) (2624x2048 f16, Wq rows 0..2559 + Wr rows 2560..2623)
  //  stable : qkvr16[27.53M,49.02M) (4096x2624 f16)  lam[49.02M)
  //  phase 2: Qo[0,16.78M) Ko[16.78M,20.97M) Vto[20.97M,25.17M) (alias phase 1)
  char* ws = (char*)d_ws;
  f16*   xb     = (f16*)  (ws + 0);
  f16*   wt     = (f16*)  (ws + 16777216);
  f16*   qkvr16 = (f16*)  (ws + 27525120);
  float* lam    = (float*)(ws + 49020928);
  f16*   Qo     = (f16*)  (ws + 0);
  f16*   Ko     = (f16*)  (ws + 16777216);
  f16*   Vto    = (f16*)  (ws + 20971520);

  k_cast_f16<<<dim3(8192), dim3(256), 0, stream>>>(x, xb, 2097152);
  k_transpose_f16<<<dim3(80, 64), dim3(256), 0, stream>>>(Wq, wt, 2048, 2560);
  k_transpose_f16<<<dim3(2, 64), dim3(256), 0, stream>>>(Wr, wt + (size_t)2560 * 2048, 2048, 64);
  gemm_bt_kernel<128, 64, 4, 1><<<dim3(41, 32), dim3(256), 0, stream>>>(
      xb, wt, qkvr16, 4096, 2624, 2048);
  k_lambda<<<dim3(1), dim3(64), 0, stream>>>(lq1, lk1, lq2, lk2, lam);
  k_build<<<dim3(4096), dim3(256), 0, stream>>>(qkvr16, br, sc, Qo, Ko, Vto);
  flash_kernel<<<dim3(64, 8, 2), dim3(128), 0, stream>>>(Qo, Ko, Vto, lam, out);
}